// Round 8
// baseline (1296.660 us; speedup 1.0000x reference)
//
#include <hip/hip_runtime.h>

#define NN 128
#define ME 32
#define DI 64
#define NZ 96
#define ROWD 130
#define MAXIT 5000

// ---- LDS (double idx). R: [0,16640). Loop buffers live inside the R region
// (R is dead after setup; finals use global RBt from workspace).
#define PPK_A   0        // [2][3][64] packed (lo,hi) f32 partials (1 dbl slot each)
#define PPK_B   384
#define ZEXLF_A 1536     // FLOAT idx: [2][64] f32 z_lo publish (w0 -> w3)
#define ZEXHF_A 1664     // FLOAT idx: [2][32]
#define ZEXLF_B 1728
#define ZEXHF_B 1856     // ends f-idx 1920 = dbl 960
#define TVX_A   960      // [2][64] f64 tv terms (w3)
#define TVX_B   1088
#define TV16_A  1216     // [2][16]
#define TV16_B  1248
#define FLG_A   1280     // [2]
#define FLG_B   1282
#define ZBF_A   1284     // [96] final z publish
#define ZBF_B   1380
// ---- upper region (transients reused per pass + per-chain persistents)
#define OFF_UN 16640
#define ROWB  (OFF_UN)          // [2][128] sweep
#define COLB  (OFF_UN + 256)    // [2][128] sweep
#define YBUF  (OFF_UN)          // [128][12] f64 (stage 2)
#define KBUFF (2*(OFF_UN + 1536)) // FLOAT idx: [12][96] f32 (stage 2)
#define CPART (OFF_UN)          // [2][128] (stage 3a)
#define CBT   (OFF_UN + 256)    // [128] c (transient)
#define QBUF  (OFF_UN + 384)    // [128] q (transient)
#define VP    (OFF_UN + 512)    // [4][128] (stage 3b)
#define V2T   (OFF_UN + 1024)   // [128] Rq (transient)
#define FPART (OFF_UN)          // [2][128] (final)
#define PBASE (OFF_UN + 2112)   // per-chain persistents: HB(64) BB(32) BASEV(96) QBV(96) V1(128) CST(2)
#define PCH   418
#define LDS_DBL (PBASE + 2*PCH) // 19588 dbl = 156704 B <= 163840

typedef __attribute__((ext_vector_type(2))) float f32x2;

// f32 SGPR broadcast. CONTRACT: source computed by all lanes of the wave.
__device__ __forceinline__ float rlf(float v, int lane) {
  return __uint_as_float((unsigned)__builtin_amdgcn_readlane((int)__float_as_uint(v), lane));
}
__device__ __forceinline__ f32x2 fma2(f32x2 a, f32x2 b, f32x2 c) {
  return __builtin_elementwise_fma(a, b, c);   // v_pk_fma_f32
}

// matvec step: 2 pairs (4 cols) with broadcast lanes L0..L0+3 of ZS
#define MV2(KP, KP2, PA, ZS, L0) {                                          \
    f32x2 z0 = { rlf(ZS, L0), rlf(ZS, (L0)+1) };                            \
    A0 = fma2(KP[PA], z0, A0); B0 = fma2(KP2[PA], z0, B0);                  \
    f32x2 z1 = { rlf(ZS, (L0)+2), rlf(ZS, (L0)+3) };                        \
    A1 = fma2(KP[(PA)+1], z1, A1); B1 = fma2(KP2[(PA)+1], z1, B1); }

#define BURST_LO_A(KP, KP2, Z)  /* cols 0..31 */                            \
    MV2(KP,KP2,0,Z,0)  MV2(KP,KP2,2,Z,4)  MV2(KP,KP2,4,Z,8)  MV2(KP,KP2,6,Z,12) \
    MV2(KP,KP2,8,Z,16) MV2(KP,KP2,10,Z,20) MV2(KP,KP2,12,Z,24) MV2(KP,KP2,14,Z,28)
#define BURST_LO_B(KP, KP2, Z)  /* cols 32..63 */                           \
    MV2(KP,KP2,0,Z,32) MV2(KP,KP2,2,Z,36) MV2(KP,KP2,4,Z,40) MV2(KP,KP2,6,Z,44) \
    MV2(KP,KP2,8,Z,48) MV2(KP,KP2,10,Z,52) MV2(KP,KP2,12,Z,56) MV2(KP,KP2,14,Z,60)
#define BURST_HI(KP, KP2, Z)    /* hi cols 0..31 */                         \
    MV2(KP,KP2,0,Z,0)  MV2(KP,KP2,2,Z,4)  MV2(KP,KP2,4,Z,8)  MV2(KP,KP2,6,Z,12) \
    MV2(KP,KP2,8,Z,16) MV2(KP,KP2,10,Z,20) MV2(KP,KP2,12,Z,24) MV2(KP,KP2,14,Z,28)

// copy KBUFF cols [KBASE, KBASE+CNT) into local K pairs starting at local col LBASE
#define CPYRANGE(KP, KP2, LBASE, KBASE, CNT)                                \
  _Pragma("unroll") for (int j = 0; j < (CNT); ++j) {                       \
    const int lj = (LBASE) + j, kc = (KBASE) + j;                           \
    float va = ldsf[KBUFF + kc*NZ + l];                                     \
    float vb = ldsf[KBUFF + kc*NZ + 64 + lm];                               \
    if ((lj & 1) == 0) { KP[lj>>1].x = va; KP2[lj>>1].x = vb; }             \
    else               { KP[lj>>1].y = va; KP2[lj>>1].y = vb; }             \
  }

#define KCOPY_ARMS(KP, KP2)                                                 \
  if (w == 0) {                                                             \
    if (blk == 0)      { CPYRANGE(KP,KP2,0,  0, 12) }                       \
    else if (blk == 1) { CPYRANGE(KP,KP2,12, 0, 12) }                       \
    else if (blk == 2) { CPYRANGE(KP,KP2,24, 0, 8) }                        \
  } else if (w == 1) {                                                      \
    if (blk == 2)      { CPYRANGE(KP,KP2,0,  8, 4) }                        \
    else if (blk == 3) { CPYRANGE(KP,KP2,4,  0, 12) }                       \
    else if (blk == 4) { CPYRANGE(KP,KP2,16, 0, 12) }                       \
    else if (blk == 5) { CPYRANGE(KP,KP2,28, 0, 4) }                        \
  } else if (w == 2) {                                                      \
    if (blk == 5)      { CPYRANGE(KP,KP2,0,  4, 8) }                        \
    else if (blk == 6) { CPYRANGE(KP,KP2,8,  0, 12) }                       \
    else if (blk == 7) { CPYRANGE(KP,KP2,20, 0, 12) }                       \
  }

__global__ __launch_bounds__(256, 1) void altdiff_kernel(
    const float* __restrict__ Qg, const float* __restrict__ qg,
    const float* __restrict__ Gg, const float* __restrict__ hg,
    const float* __restrict__ Ag, const float* __restrict__ bg,
    float* __restrict__ out, float* __restrict__ wsf)
{
  extern __shared__ double ldsd[];
  float* const ldsf = (float*)ldsd;

  const int bidx = blockIdx.x;
  const int tid  = threadIdx.x;
  const int w    = tid >> 6;     // wave 0..3
  const int l    = tid & 63;     // lane
  const int lm   = l & 31;
  const int ia   = tid & 127;    // 128-split index
  const int hh   = tid >> 7;     // 0..1 (wave-uniform)
  const int r = tid >> 4, c = tid & 15;   // 8x8 register tile

  f32x2 KpA[16], Kp2A[16], KpB[16], Kp2B[16];   // loop K regs, both chains

  // ================= SETUP: two sequential passes (chain g = 0,1) =================
  for (int g = 0; g < 2; ++g) {
    const int ch = 2*bidx + g;
    const float* Qb = Qg + (size_t)ch * NN * NN;
    const float* Ab = Ag + (size_t)ch * ME * NN;
    const float* Gb = Gg + (size_t)ch * DI * NN;
    const float* qb = qg + (size_t)ch * NN;
    const float* hb = hg + (size_t)ch * DI;
    const float* bv = bg + (size_t)ch * ME;
    const int PG = PBASE + g*PCH;         // persistent block: HB+0 BB+64 BASEV+96 QBV+192 V1+288 CST+416

    // stage h, b (persistent, per chain)
    if (tid < DI) ldsd[PG + tid] = (double)hb[tid];
    else if (tid < DI + ME) ldsd[PG + 64 + tid - DI] = (double)bv[tid - DI];

    double acc[8][8];
    // -------- Phase 1: M = Q + A^T A + G^T G (f64) -> registers --------
    {
      const float4* Q4 = (const float4*)Qb;
#pragma unroll
      for (int rr = 0; rr < 8; ++rr) {
        float4 q0 = Q4[((8*r+rr) << 5) + 2*c];
        float4 q1 = Q4[((8*r+rr) << 5) + 2*c + 1];
        acc[rr][0]=(double)q0.x; acc[rr][1]=(double)q0.y; acc[rr][2]=(double)q0.z; acc[rr][3]=(double)q0.w;
        acc[rr][4]=(double)q1.x; acc[rr][5]=(double)q1.y; acc[rr][6]=(double)q1.z; acc[rr][7]=(double)q1.w;
      }
      const float4* A4 = (const float4*)Ab;
      for (int m = 0; m < ME; ++m) {
        float4 u0 = A4[(m << 5) + 2*r], u1 = A4[(m << 5) + 2*r + 1];
        float4 v0 = A4[(m << 5) + 2*c], v1 = A4[(m << 5) + 2*c + 1];
        double uu[8] = {(double)u0.x,(double)u0.y,(double)u0.z,(double)u0.w,
                        (double)u1.x,(double)u1.y,(double)u1.z,(double)u1.w};
        double vv[8] = {(double)v0.x,(double)v0.y,(double)v0.z,(double)v0.w,
                        (double)v1.x,(double)v1.y,(double)v1.z,(double)v1.w};
#pragma unroll
        for (int rr = 0; rr < 8; ++rr)
#pragma unroll
          for (int cc = 0; cc < 8; ++cc)
            acc[rr][cc] = fma(uu[rr], vv[cc], acc[rr][cc]);
      }
      const float4* G4 = (const float4*)Gb;
      for (int d = 0; d < DI; ++d) {
        float4 u0 = G4[(d << 5) + 2*r], u1 = G4[(d << 5) + 2*r + 1];
        float4 v0 = G4[(d << 5) + 2*c], v1 = G4[(d << 5) + 2*c + 1];
        double uu[8] = {(double)u0.x,(double)u0.y,(double)u0.z,(double)u0.w,
                        (double)u1.x,(double)u1.y,(double)u1.z,(double)u1.w};
        double vv[8] = {(double)v0.x,(double)v0.y,(double)v0.z,(double)v0.w,
                        (double)v1.x,(double)v1.y,(double)v1.z,(double)v1.w};
#pragma unroll
        for (int rr = 0; rr < 8; ++rr)
#pragma unroll
          for (int cc = 0; cc < 8; ++cc)
            acc[rr][cc] = fma(uu[rr], vv[cc], acc[rr][cc]);
      }
    }

    // -------- Phase 2: register-tile sweep (R = -M^{-1}), 1 barrier/pivot --------
    {
      if (r == 0) {
#pragma unroll
        for (int cc = 0; cc < 8; ++cc) ldsd[ROWB + 8*c + cc] = acc[0][cc];
      }
      if (c == 0) {
#pragma unroll
        for (int rr = 0; rr < 8; ++rr) ldsd[COLB + 8*r + rr] = acc[rr][0];
      }
      __syncthreads();
      for (int k = 0; k < NN; ++k) {
        const int pb = (k & 1) << 7;
        const int krt = k >> 3, kcl = k & 7;
        double rowk[8], colv[8];
#pragma unroll
        for (int cc = 0; cc < 8; ++cc) rowk[cc] = ldsd[ROWB + pb + 8*c + cc];
#pragma unroll
        for (int rr = 0; rr < 8; ++rr) colv[rr] = ldsd[COLB + pb + 8*r + rr];
        const double dkk  = ldsd[ROWB + pb + k];
        const double rcpd = 1.0 / dkk;               // pivots >= 1 (M >= I)
        double rdv[8];
#pragma unroll
        for (int cc = 0; cc < 8; ++cc) rdv[cc] = rowk[cc] * rcpd;
        const bool pivR = (r == krt), pivC = (c == krt);
#pragma unroll
        for (int rr = 0; rr < 8; ++rr) {
          const double cv = colv[rr] * rcpd;
          const bool pr = pivR && (rr == kcl);
#pragma unroll
          for (int cc = 0; cc < 8; ++cc) {
            double gen = fma(-cv, rowk[cc], acc[rr][cc]);
            acc[rr][cc] = pr ? rdv[cc] : gen;
          }
        }
        if (pivC) {
#pragma unroll
          for (int cc = 0; cc < 8; ++cc) if (cc == kcl) {
#pragma unroll
            for (int rr = 0; rr < 8; ++rr) {
              const bool pr2 = pivR && (rr == kcl);
              acc[rr][cc] = pr2 ? -rcpd : colv[rr] * rcpd;
            }
          }
        }
        if (k < NN - 1) {
          const int pb2 = ((k + 1) & 1) << 7;
          const int krt2 = (k + 1) >> 3, kcl2 = (k + 1) & 7;
          if (r == krt2) {
#pragma unroll
            for (int rr = 0; rr < 8; ++rr) if (rr == kcl2) {
#pragma unroll
              for (int cc = 0; cc < 8; ++cc) ldsd[ROWB + pb2 + 8*c + cc] = acc[rr][cc];
            }
          }
          if (c == krt2) {
#pragma unroll
            for (int cc = 0; cc < 8; ++cc) if (cc == kcl2) {
#pragma unroll
              for (int rr = 0; rr < 8; ++rr) ldsd[COLB + pb2 + 8*r + rr] = acc[rr][cc];
            }
          }
        }
        __syncthreads();
      }
#pragma unroll
      for (int rr = 0; rr < 8; ++rr) {
        double2* dst = (double2*)(ldsd + (8*r+rr)*ROWD + 8*c);
#pragma unroll
        for (int t = 0; t < 4; ++t) dst[t] = make_double2(acc[rr][2*t], acc[rr][2*t+1]);
      }
    }
    __syncthreads();

    // -------- Stage 2: Y = R B^T (streamed to ws as RBt f32), K = B Y --------
    for (int blk = 0; blk < 8; ++blk) {
      {
        const float* gp[6];
#pragma unroll
        for (int jj = 0; jj < 6; ++jj) {
          int it = 12*blk + 6*hh + jj;
          gp[jj] = (it < DI) ? (Gb + it*NN) : (Ab + (it - DI)*NN);
        }
        double a2[6] = {0,0,0,0,0,0};
#pragma unroll 4
        for (int t = 0; t < NN; ++t) {
          double rv = ldsd[t*ROWD + ia];
#pragma unroll
          for (int jj = 0; jj < 6; ++jj)
            a2[jj] = fma(rv, (double)gp[jj][t], a2[jj]);
        }
        double2* yst = (double2*)(ldsd + YBUF + ia*12 + 6*hh);
#pragma unroll
        for (int p = 0; p < 3; ++p) yst[p] = make_double2(a2[2*p], a2[2*p+1]);
        // RBt stream to workspace: col-major [col][ia], f32
        float* rbt = wsf + (size_t)ch * (96*128);
#pragma unroll
        for (int jj = 0; jj < 6; ++jj)
          rbt[(12*blk + 6*hh + jj)*128 + ia] = (float)a2[jj];
      }
      __syncthreads();
      {
        const int r2 = (ia < NZ) ? ia : 0;
        const float* brow = (r2 < DI) ? (Gb + r2*NN) : (Ab + (r2 - DI)*NN);
        double a2[6] = {0,0,0,0,0,0};
#pragma unroll 4
        for (int t = 0; t < NN; ++t) {
          double bvv = (double)brow[t];
          const double2* yr = (const double2*)(ldsd + YBUF + t*12 + 6*hh);
          double2 y0 = yr[0], y1 = yr[1], y2 = yr[2];
          a2[0] = fma(bvv, y0.x, a2[0]); a2[1] = fma(bvv, y0.y, a2[1]);
          a2[2] = fma(bvv, y1.x, a2[2]); a2[3] = fma(bvv, y1.y, a2[3]);
          a2[4] = fma(bvv, y2.x, a2[4]); a2[5] = fma(bvv, y2.y, a2[5]);
        }
        if (ia < NZ) {
#pragma unroll
          for (int jj = 0; jj < 6; ++jj) ldsf[KBUFF + (6*hh + jj)*NZ + ia] = (float)a2[jj];
        }
      }
      __syncthreads();
      if (g == 0) { KCOPY_ARMS(KpA, Kp2A) } else { KCOPY_ARMS(KpB, Kp2B) }
      __syncthreads();
    }

    // -------- Stage 3a: c = q - G^T h - A^T b --------
    if (tid < NN) ldsd[QBUF + tid] = (double)qb[tid];
    {
      double s = 0;
#pragma unroll 8
      for (int jc = 0; jc < 48; ++jc) {
        int j = 48*hh + jc;
        double coef = (j < DI) ? ldsd[PG + j] : ldsd[PG + 64 + j - DI];
        const float* src = (j < DI) ? (Gb + j*NN) : (Ab + (j - DI)*NN);
        s = fma(-(double)src[ia], coef, s);
      }
      ldsd[CPART + hh*128 + ia] = s;
    }
    __syncthreads();
    if (tid < NN) ldsd[CBT + tid] = ldsd[QBUF + tid] + ldsd[CPART + tid] + ldsd[CPART + 128 + tid];
    __syncthreads();

    // -------- Stage 3b: v1 = R c, v2 = R q --------
    {
      double a = 0, b2 = 0;
#pragma unroll 4
      for (int tt = 0; tt < 64; ++tt) {
        int t = 64*hh + tt;
        double rv = ldsd[t*ROWD + ia];
        a  = fma(rv, ldsd[CBT + t], a);
        b2 = fma(rv, ldsd[QBUF + t], b2);
      }
      ldsd[VP + hh*128 + ia] = a;
      ldsd[VP + 256 + hh*128 + ia] = b2;
    }
    __syncthreads();
    if (tid < NN) {
      ldsd[PG + 288 + tid] = ldsd[VP + tid] + ldsd[VP + 128 + tid];       // V1 (persistent)
      ldsd[V2T + tid]      = ldsd[VP + 256 + tid] + ldsd[VP + 384 + tid]; // V2 (transient)
    }
    __syncthreads();

    // -------- Stage 3c: base = B v1, qB = B v2, scalars --------
    {
      const int r2 = (ia < NZ) ? ia : 0;
      const float* brow = (r2 < DI) ? (Gb + r2*NN) : (Ab + (r2 - DI)*NN);
      const int voff = hh ? V2T : (PG + 288);
      double s = 0;
#pragma unroll 4
      for (int t = 0; t < NN; ++t) s = fma((double)brow[t], ldsd[voff + t], s);
      if (ia < NZ) ldsd[(hh ? (PG + 192) : (PG + 96)) + ia] = s;          // QBV : BASEV
    }
    if (w == 0) {
      double pc = ldsd[PG+288+l]*ldsd[CBT+l]  + ldsd[PG+288+64+l]*ldsd[CBT+64+l];
      double pq = ldsd[PG+288+l]*ldsd[QBUF+l] + ldsd[PG+288+64+l]*ldsd[QBUF+64+l];
#pragma unroll
      for (int off = 32; off >= 1; off >>= 1) { pc += __shfl_xor(pc, off); pq += __shfl_xor(pq, off); }
      if (l == 0) { ldsd[PG + 416] = pc; ldsd[PG + 417] = pq; }
    }
    __syncthreads();
  } // end setup passes

  // ================= Loop state (both chains) =================
  const int PA_ = PBASE, PB_ = PBASE + PCH;
  const double baseA_lo = ldsd[PA_+96 + l],  baseA_hi = ldsd[PA_+96 + 64 + lm];
  const double qvA_lo   = ldsd[PA_+192 + l], qvA_hi   = ldsd[PA_+192 + 64 + lm];
  const double hbA2 = ldsd[PA_ + l] - baseA_lo;
  const double bbA2 = baseA_hi - ldsd[PA_+64 + lm];
  const double S_ucA = ldsd[PA_+416], S_quA = ldsd[PA_+417];
  const double baseB_lo = ldsd[PB_+96 + l],  baseB_hi = ldsd[PB_+96 + 64 + lm];
  const double qvB_lo   = ldsd[PB_+192 + l], qvB_hi   = ldsd[PB_+192 + 64 + lm];
  const double hbB2 = ldsd[PB_ + l] - baseB_lo;
  const double bbB2 = baseB_hi - ldsd[PB_+64 + lm];
  const double S_ucB = ldsd[PB_+416], S_quB = ldsd[PB_+417];

  double hnbA = hbA2, lbA = bbA2, hnbB = hbB2, lbB = bbB2;
  float hnbfA = (float)hnbA, lbfA = (float)lbA, hnbfB = (float)hnbB, lbfB = (float)lbB;
  float2 ownA = make_float2(0.f, 0.f), ownB = make_float2(0.f, 0.f);
  float zAfA_lo=0.f, zAfA_hi=0.f, zBfA_lo=0.f, zBfA_hi=0.f, zCfA_lo=0.f, zCfA_hi=0.f;
  float zAfB_lo=0.f, zAfB_hi=0.f, zBfB_lo=0.f, zBfB_hi=0.f, zCfB_lo=0.f, zCfB_hi=0.f;
  double res_prevA = 1000.0, res_curA = -100.0, res_prevB = 1000.0, res_curB = -100.0;
  bool doneA = false, doneB = false;

  // prologue: zero P buf0 slots; z(-1)=0 into ZEX buf1; flags 0
  {
    if (w < 3) {
      *(float2*)&ldsd[PPK_A + w*64 + l] = make_float2(0.f, 0.f);
      *(float2*)&ldsd[PPK_B + w*64 + l] = make_float2(0.f, 0.f);
    }
    if (w == 0) { ldsf[ZEXLF_A + 64 + l] = 0.f; ldsf[ZEXLF_B + 64 + l] = 0.f; }
    if (w == 2 && l < 32) { ldsf[ZEXHF_A + 32 + l] = 0.f; ldsf[ZEXHF_B + 32 + l] = 0.f; }
    if (tid == 0) { ldsd[FLG_A] = 0.0; ldsd[FLG_A+1] = 0.0; ldsd[FLG_B] = 0.0; ldsd[FLG_B+1] = 0.0; }
  }

  // ================= Interleaved ADMM loop: 1 barrier per (pair-)body =================
  for (int it = 0; it < MAXIT + 3; ++it) {
    __syncthreads();
    const int buf = it & 1, nbuf = buf ^ 1;
    const int bprev = nbuf;
    const double flA = ldsd[FLG_A + bprev];
    const double flB = ldsd[FLG_B + bprev];
    const float2* pbA = (const float2*)(ldsd + PPK_A + buf*192);
    const float2* pbB = (const float2*)(ldsd + PPK_B + buf*192);

    if (w == 0) {
      float2 a1v = pbA[64 + l], a2v = pbA[128 + l];
      float2 b1v = pbB[64 + l], b2v = pbB[128 + l];
      float sloA = (ownA.x + a1v.x) + a2v.x;
      float zfA  = fabsf(hnbfA - sloA);
      float sloB = (ownB.x + b1v.x) + b2v.x;
      float zfB  = fabsf(hnbfB - sloB);
      doneA = doneA || (it >= 3 && flA != 0.0);
      doneB = doneB || (it >= 3 && flB != 0.0);
      if (doneA && doneB) break;
      if (!doneA && it < MAXIT) {
        ldsf[ZEXLF_A + buf*64 + l] = zfA;
        double t = hnbA - (double)sloA; hnbA = hbA2 + fmin(t, 0.0); hnbfA = (float)hnbA;
        f32x2 A0 = {0.f,0.f}, A1 = A0, B0 = A0, B1 = A0;
        BURST_LO_A(KpA, Kp2A, zfA)
        f32x2 As = A0 + A1, Bs = B0 + B1;
        float2 np = make_float2(As.x + As.y, Bs.x + Bs.y);
        *(float2*)&ldsd[PPK_A + nbuf*192 + l] = np;  ownA = np;
      }
      if (!doneB && it < MAXIT) {
        ldsf[ZEXLF_B + buf*64 + l] = zfB;
        double t = hnbB - (double)sloB; hnbB = hbB2 + fmin(t, 0.0); hnbfB = (float)hnbB;
        f32x2 A0 = {0.f,0.f}, A1 = A0, B0 = A0, B1 = A0;
        BURST_LO_A(KpB, Kp2B, zfB)
        f32x2 As = A0 + A1, Bs = B0 + B1;
        float2 np = make_float2(As.x + As.y, Bs.x + Bs.y);
        *(float2*)&ldsd[PPK_B + nbuf*192 + l] = np;  ownB = np;
      }
    } else if (w == 1) {
      float2 a0v = pbA[l], a2v = pbA[128 + l];
      float2 b0v = pbB[l], b2v = pbB[128 + l];
      float sloA = (a0v.x + ownA.x) + a2v.x;
      float zfA  = fabsf(hnbfA - sloA);
      float sloB = (b0v.x + ownB.x) + b2v.x;
      float zfB  = fabsf(hnbfB - sloB);
      doneA = doneA || (it >= 3 && flA != 0.0);
      doneB = doneB || (it >= 3 && flB != 0.0);
      if (doneA && doneB) break;
      if (!doneA && it < MAXIT) {
        double t = hnbA - (double)sloA; hnbA = hbA2 + fmin(t, 0.0); hnbfA = (float)hnbA;
        f32x2 A0 = {0.f,0.f}, A1 = A0, B0 = A0, B1 = A0;
        BURST_LO_B(KpA, Kp2A, zfA)
        f32x2 As = A0 + A1, Bs = B0 + B1;
        float2 np = make_float2(As.x + As.y, Bs.x + Bs.y);
        *(float2*)&ldsd[PPK_A + nbuf*192 + 64 + l] = np;  ownA = np;
      }
      if (!doneB && it < MAXIT) {
        double t = hnbB - (double)sloB; hnbB = hbB2 + fmin(t, 0.0); hnbfB = (float)hnbB;
        f32x2 A0 = {0.f,0.f}, A1 = A0, B0 = A0, B1 = A0;
        BURST_LO_B(KpB, Kp2B, zfB)
        f32x2 As = A0 + A1, Bs = B0 + B1;
        float2 np = make_float2(As.x + As.y, Bs.x + Bs.y);
        *(float2*)&ldsd[PPK_B + nbuf*192 + 64 + l] = np;  ownB = np;
      }
    } else if (w == 2) {
      float2 a0v = pbA[l], a1v = pbA[64 + l];
      float2 b0v = pbB[l], b1v = pbB[64 + l];
      float shiA = (a0v.y + a1v.y) + ownA.y;
      float zfA  = lbfA + shiA;
      float shiB = (b0v.y + b1v.y) + ownB.y;
      float zfB  = lbfB + shiB;
      doneA = doneA || (it >= 3 && flA != 0.0);
      doneB = doneB || (it >= 3 && flB != 0.0);
      if (doneA && doneB) break;
      if (!doneA && it < MAXIT) {
        if (l < 32) ldsf[ZEXHF_A + buf*32 + l] = zfA;
        double lamn = lbA + (double)shiA; lbA = lamn + bbA2; lbfA = (float)lbA;
        f32x2 A0 = {0.f,0.f}, A1 = A0, B0 = A0, B1 = A0;
        BURST_HI(KpA, Kp2A, zfA)
        f32x2 As = A0 + A1, Bs = B0 + B1;
        float2 np = make_float2(As.x + As.y, Bs.x + Bs.y);
        *(float2*)&ldsd[PPK_A + nbuf*192 + 128 + l] = np;  ownA = np;
      }
      if (!doneB && it < MAXIT) {
        if (l < 32) ldsf[ZEXHF_B + buf*32 + l] = zfB;
        double lamn = lbB + (double)shiB; lbB = lamn + bbB2; lbfB = (float)lbB;
        f32x2 A0 = {0.f,0.f}, A1 = A0, B0 = A0, B1 = A0;
        BURST_HI(KpB, Kp2B, zfB)
        f32x2 As = A0 + A1, Bs = B0 + B1;
        float2 np = make_float2(As.x + As.y, Bs.x + Bs.y);
        *(float2*)&ldsd[PPK_B + nbuf*192 + 128 + l] = np;  ownB = np;
      }
    } else {
      // -------- w3: objective pipelines + z rings (both chains) --------
      float2 vA0 = pbA[l], vA1 = pbA[64 + l], vA2 = pbA[128 + l];
      float2 vB0 = pbB[l], vB1 = pbB[64 + l], vB2 = pbB[128 + l];
      const float ztlA = ldsf[ZEXLF_A + bprev*64 + l];
      const float zthA = ldsf[ZEXHF_A + bprev*32 + lm];
      const float ztlB = ldsf[ZEXLF_B + bprev*64 + l];
      const float zthB = ldsf[ZEXHF_B + bprev*32 + lm];
      const int g2 = l & 15;
      const double* tqA = ldsd + TVX_A + bprev*64;
      double aA0 = tqA[g2], aA1 = tqA[g2+16], aA2 = tqA[g2+32], aA3 = tqA[g2+48];
      const double* tqB = ldsd + TVX_B + bprev*64;
      double aB0 = tqB[g2], aB1 = tqB[g2+16], aB2 = tqB[g2+32], aB3 = tqB[g2+48];
      double t1A[16], t1B[16];
      {
        const double2* tpA = (const double2*)(ldsd + TV16_A + bprev*16);
        const double2* tpB = (const double2*)(ldsd + TV16_B + bprev*16);
#pragma unroll
        for (int u = 0; u < 8; ++u) {
          double2 va = tpA[u]; t1A[2*u] = va.x; t1A[2*u+1] = va.y;
          double2 vb = tpB[u]; t1B[2*u] = vb.x; t1B[2*u+1] = vb.y;
        }
      }
      doneA = doneA || (it >= 3 && flA != 0.0);
      doneB = doneB || (it >= 3 && flB != 0.0);
      if (doneA && doneB) break;
      if (!doneA) {
        zCfA_lo = zBfA_lo; zCfA_hi = zBfA_hi; zBfA_lo = zAfA_lo; zBfA_hi = zAfA_hi;
        zAfA_lo = ztlA;    zAfA_hi = zthA;
        if (it < MAXIT) {
          float slo_f = (vA0.x + vA1.x) + vA2.x;
          float shi_f = (vA0.y + vA1.y) + vA2.y;
          double zAl = (double)zAfA_lo;
          double yf  = (double)slo_f + baseA_lo;
          double tvl = fma(qvA_lo, zAl, -0.5*(zAl*(baseA_lo + yf) + yf*yf));
          double zAh = (double)zAfA_hi;
          double yfB = (double)shi_f + baseA_hi;
          double tvh = fma(qvA_hi, zAh, -0.5*(zAh*(baseA_hi + yfB) + yfB*yfB));
          ldsd[TVX_A + buf*64 + l] = tvl + ((l < 32) ? tvh : 0.0);
        }
        if (l < 16 && it >= 1 && it <= MAXIT)
          ldsd[TV16_A + buf*16 + l] = (aA0 + aA1) + (aA2 + aA3);
        if (it >= 2 && it <= MAXIT + 1) {
          double s1 = ((t1A[0]+t1A[1]) + (t1A[2]+t1A[3])) + ((t1A[4]+t1A[5]) + (t1A[6]+t1A[7]));
          double s2 = ((t1A[8]+t1A[9]) + (t1A[10]+t1A[11])) + ((t1A[12]+t1A[13]) + (t1A[14]+t1A[15]));
          double obj = (s1 + s2) - 0.5*S_ucA + S_quA;
          res_prevA = res_curA; res_curA = obj;
          if (l == 0)
            ldsd[FLG_A + buf] = (fabs(res_curA - res_prevA) <= 1e-5 * fabs(res_prevA)) ? 1.0 : 0.0;
        }
      }
      if (!doneB) {
        zCfB_lo = zBfB_lo; zCfB_hi = zBfB_hi; zBfB_lo = zAfB_lo; zBfB_hi = zAfB_hi;
        zAfB_lo = ztlB;    zAfB_hi = zthB;
        if (it < MAXIT) {
          float slo_f = (vB0.x + vB1.x) + vB2.x;
          float shi_f = (vB0.y + vB1.y) + vB2.y;
          double zAl = (double)zAfB_lo;
          double yf  = (double)slo_f + baseB_lo;
          double tvl = fma(qvB_lo, zAl, -0.5*(zAl*(baseB_lo + yf) + yf*yf));
          double zAh = (double)zAfB_hi;
          double yfB = (double)shi_f + baseB_hi;
          double tvh = fma(qvB_hi, zAh, -0.5*(zAh*(baseB_hi + yfB) + yfB*yfB));
          ldsd[TVX_B + buf*64 + l] = tvl + ((l < 32) ? tvh : 0.0);
        }
        if (l < 16 && it >= 1 && it <= MAXIT)
          ldsd[TV16_B + buf*16 + l] = (aB0 + aB1) + (aB2 + aB3);
        if (it >= 2 && it <= MAXIT + 1) {
          double s1 = ((t1B[0]+t1B[1]) + (t1B[2]+t1B[3])) + ((t1B[4]+t1B[5]) + (t1B[6]+t1B[7]));
          double s2 = ((t1B[8]+t1B[9]) + (t1B[10]+t1B[11])) + ((t1B[12]+t1B[13]) + (t1B[14]+t1B[15]));
          double obj = (s1 + s2) - 0.5*S_ucB + S_quB;
          res_prevB = res_curB; res_curB = obj;
          if (l == 0)
            ldsd[FLG_B + buf] = (fabs(res_curB - res_prevB) <= 1e-5 * fabs(res_prevB)) ? 1.0 : 0.0;
        }
      }
    }
  }

  // ================= Finals: x = v1 + RBt z (RBt f32 from workspace) =================
  if (w == 3) {
    ldsd[ZBF_A + l] = (double)zCfA_lo;
    if (l < 32) ldsd[ZBF_A + 64 + l] = (double)zCfA_hi;
    ldsd[ZBF_B + l] = (double)zCfB_lo;
    if (l < 32) ldsd[ZBF_B + 64 + l] = (double)zCfB_hi;
  }
  __syncthreads();
  for (int g = 0; g < 2; ++g) {
    const float* rbt = wsf + (size_t)(2*bidx + g) * (96*128);
    const int ZB = g ? ZBF_B : ZBF_A;
    double s = 0;
#pragma unroll 8
    for (int jc = 0; jc < 48; ++jc) {
      int j = 48*hh + jc;
      s = fma((double)rbt[j*128 + ia], ldsd[ZB + j], s);
    }
    ldsd[FPART + hh*128 + ia] = s;
    __syncthreads();
    if (tid < NN) {
      const int V1g = PBASE + g*PCH + 288;
      out[(size_t)(2*bidx + g)*NN + tid] =
          (float)(ldsd[V1g + tid] + ldsd[FPART + tid] + ldsd[FPART + 128 + tid]);
    }
    __syncthreads();
  }
}

extern "C" void kernel_launch(void* const* d_in, const int* in_sizes, int n_in,
                              void* d_out, int out_size, void* d_ws, size_t ws_size,
                              hipStream_t stream) {
  (void)in_sizes; (void)n_in; (void)out_size; (void)ws_size;
  const float* Q = (const float*)d_in[0];
  const float* q = (const float*)d_in[1];
  const float* G = (const float*)d_in[2];
  const float* h = (const float*)d_in[3];
  const float* A = (const float*)d_in[4];
  const float* b = (const float*)d_in[5];
  float* out = (float*)d_out;
  float* ws  = (float*)d_ws;    // needs 64*96*128*4 = 3,145,728 B
  const size_t lds_bytes = (size_t)LDS_DBL * sizeof(double);  // 156704
  altdiff_kernel<<<dim3(32), dim3(256), lds_bytes, stream>>>(Q, q, G, h, A, b, out, ws);
}

// Round 9
// 653.115 us; speedup vs baseline: 1.9853x; 1.9853x over previous
//
#include <hip/hip_runtime.h>

#define NN 128
#define ME 32
#define DI 64
#define NZ 96
#define ROWD 130
#define MAXIT 5000

// ---- LDS layout (double offsets). R: [0, 16640). Total 20040 dbl = 160320 B <= 163840.
#define OFF_UN 16640
#define ROWB  (OFF_UN)           // [2][128] sweep row-k buffer (phase 2)
#define COLB  (OFF_UN + 256)     // [2][128] sweep col-k buffer (phase 2)
// loop window (4-slot exchange; obj stages distributed as shadow work):
#define PPK   (OFF_UN)           // [2][4][64] packed (lo,hi) f32 partials in b64 slots
#define TVX   (OFF_UN + 512)     // [2][64] f64 per-lane tv terms (w2 -> w1)
#define TV16  (OFF_UN + 640)     // [2][16] f64 stage-A sums (w1 -> w3)
#define FLG   (OFF_UN + 672)     // [2] convergence flag (double 0/1)
#define YBUF  (OFF_UN)           // [128][12] Y block (stage 2; dead before loop)
#define KBUF  (OFF_UN + 1536)    // [12][96] K cols (stage 2; dead before loop)
#define CPART (OFF_UN + 1024)    // [2][128] (stage 3a)
#define VP    (OFF_UN + 1280)    // [4][128] (stage 3b)
#define BASEV (OFF_UN + 1792)    // [96] (persists through loop)
#define QBV   (OFF_UN + 1888)    // [96] (persists through loop)
#define FPART (OFF_UN + 1024)    // [2][128] (final)
#define RHSV  (OFF_UN + 1280)    // [128] (final)
#define XPART (OFF_UN + 1408)    // [2][128] (final)
#define CB    (OFF_UN + 2688)    // [128] c
#define QBUF  (OFF_UN + 2816)    // [128] q
#define V1    (OFF_UN + 2944)    // [128] Rc
#define V2    (OFF_UN + 3072)    // [128] Rq
#define HB    (OFF_UN + 3200)    // [64]
#define BB    (OFF_UN + 3264)    // [32]
#define CST   (OFF_UN + 3296)    // [8]: 0=u.c 1=q.u
#define ZBF   (OFF_UN + 3304)    // [96] z publish (final)
#define LDS_DBL (OFF_UN + 3400)  // 20040

typedef __attribute__((ext_vector_type(2))) float f32x2;

// f32 SGPR broadcast. CONTRACT: source computed by all lanes of the wave.
__device__ __forceinline__ float rlf(float v, int lane) {
  return __uint_as_float((unsigned)__builtin_amdgcn_readlane((int)__float_as_uint(v), lane));
}
__device__ __forceinline__ f32x2 fma2(f32x2 a, f32x2 b, f32x2 c) {
  return __builtin_elementwise_fma(a, b, c);   // v_pk_fma_f32
}

// matvec step: 2 pairs (4 cols) with broadcast lanes L0..L0+3 of ZS
#define MV2(PA, ZS, L0) {                                                  \
    f32x2 z0 = { rlf(ZS, L0), rlf(ZS, (L0)+1) };                           \
    A0 = fma2(Kp[PA], z0, A0); B0 = fma2(Kp2[PA], z0, B0);                 \
    f32x2 z1 = { rlf(ZS, (L0)+2), rlf(ZS, (L0)+3) };                       \
    A1 = fma2(Kp[(PA)+1], z1, A1); B1 = fma2(Kp2[(PA)+1], z1, B1); }

// copy 12 KBUF cols (0..11 of current blk) into local pairs LB..LB+5
#define CPY12(LB)                                                          \
  _Pragma("unroll") for (int p = 0; p < 6; ++p) {                          \
    Kp [(LB)+p].x = (float)ldsd[KBUF + (2*p  )*NZ + l];                    \
    Kp [(LB)+p].y = (float)ldsd[KBUF + (2*p+1)*NZ + l];                    \
    Kp2[(LB)+p].x = (float)ldsd[KBUF + (2*p  )*NZ + 64 + lm];              \
    Kp2[(LB)+p].y = (float)ldsd[KBUF + (2*p+1)*NZ + 64 + lm];              \
  }

__global__ __launch_bounds__(256, 1) void altdiff_kernel(
    const float* __restrict__ Qg, const float* __restrict__ qg,
    const float* __restrict__ Gg, const float* __restrict__ hg,
    const float* __restrict__ Ag, const float* __restrict__ bg,
    float* __restrict__ out)
{
  extern __shared__ double ldsd[];

  const int bidx = blockIdx.x;
  const int tid  = threadIdx.x;
  const int w    = tid >> 6;     // wave 0..3
  const int l    = tid & 63;     // lane
  const int lm   = l & 31;
  const int ia   = tid & 127;    // 128-split index
  const int hh   = tid >> 7;     // 0..1 (wave-uniform)

  const float* Qb = Qg + (size_t)bidx * NN * NN;
  const float* Ab = Ag + (size_t)bidx * ME * NN;
  const float* Gb = Gg + (size_t)bidx * DI * NN;
  const float* qb = qg + (size_t)bidx * NN;
  const float* hb = hg + (size_t)bidx * DI;
  const float* bv = bg + (size_t)bidx * ME;

  // stage h, b, q (f64)
  if (tid < DI) ldsd[HB + tid] = (double)hb[tid];
  else if (tid < DI + ME) ldsd[BB + tid - DI] = (double)bv[tid - DI];
  if (tid >= 128) ldsd[QBUF + tid - 128] = (double)qb[tid - 128];

  const int r = tid >> 4, c = tid & 15;   // 8x8 register tile at rows 8r.., cols 8c..
  double acc[8][8];                       // ALL indices compile-time constant (no scratch)

  // ---------------- Phase 1: M = Q + A^T A + G^T G (f64) -> registers ----------------
  {
    const float4* Q4 = (const float4*)Qb;
#pragma unroll
    for (int rr = 0; rr < 8; ++rr) {
      float4 q0 = Q4[((8*r+rr) << 5) + 2*c];
      float4 q1 = Q4[((8*r+rr) << 5) + 2*c + 1];
      acc[rr][0]=(double)q0.x; acc[rr][1]=(double)q0.y; acc[rr][2]=(double)q0.z; acc[rr][3]=(double)q0.w;
      acc[rr][4]=(double)q1.x; acc[rr][5]=(double)q1.y; acc[rr][6]=(double)q1.z; acc[rr][7]=(double)q1.w;
    }
    const float4* A4 = (const float4*)Ab;
    for (int m = 0; m < ME; ++m) {
      float4 u0 = A4[(m << 5) + 2*r], u1 = A4[(m << 5) + 2*r + 1];
      float4 v0 = A4[(m << 5) + 2*c], v1 = A4[(m << 5) + 2*c + 1];
      double uu[8] = {(double)u0.x,(double)u0.y,(double)u0.z,(double)u0.w,
                      (double)u1.x,(double)u1.y,(double)u1.z,(double)u1.w};
      double vv[8] = {(double)v0.x,(double)v0.y,(double)v0.z,(double)v0.w,
                      (double)v1.x,(double)v1.y,(double)v1.z,(double)v1.w};
#pragma unroll
      for (int rr = 0; rr < 8; ++rr)
#pragma unroll
        for (int cc = 0; cc < 8; ++cc)
          acc[rr][cc] = fma(uu[rr], vv[cc], acc[rr][cc]);
    }
    const float4* G4 = (const float4*)Gb;
    for (int d = 0; d < DI; ++d) {
      float4 u0 = G4[(d << 5) + 2*r], u1 = G4[(d << 5) + 2*r + 1];
      float4 v0 = G4[(d << 5) + 2*c], v1 = G4[(d << 5) + 2*c + 1];
      double uu[8] = {(double)u0.x,(double)u0.y,(double)u0.z,(double)u0.w,
                      (double)u1.x,(double)u1.y,(double)u1.z,(double)u1.w};
      double vv[8] = {(double)v0.x,(double)v0.y,(double)v0.z,(double)v0.w,
                      (double)v1.x,(double)v1.y,(double)v1.z,(double)v1.w};
#pragma unroll
      for (int rr = 0; rr < 8; ++rr)
#pragma unroll
        for (int cc = 0; cc < 8; ++cc)
          acc[rr][cc] = fma(uu[rr], vv[cc], acc[rr][cc]);
    }
  }

  // ---------------- Phase 2: register-tile sweep, 1 barrier/pivot, double-buffered ----------
  {
    if (r == 0) {
#pragma unroll
      for (int cc = 0; cc < 8; ++cc) ldsd[ROWB + 8*c + cc] = acc[0][cc];
    }
    if (c == 0) {
#pragma unroll
      for (int rr = 0; rr < 8; ++rr) ldsd[COLB + 8*r + rr] = acc[rr][0];
    }
    __syncthreads();
    for (int k = 0; k < NN; ++k) {
      const int pb = (k & 1) << 7;
      const int krt = k >> 3, kcl = k & 7;
      double rowk[8], colv[8];
#pragma unroll
      for (int cc = 0; cc < 8; ++cc) rowk[cc] = ldsd[ROWB + pb + 8*c + cc];
#pragma unroll
      for (int rr = 0; rr < 8; ++rr) colv[rr] = ldsd[COLB + pb + 8*r + rr];
      const double dkk  = ldsd[ROWB + pb + k];     // same-address broadcast
      const double rcpd = 1.0 / dkk;               // pivots >= 1 (M >= I)
      double rdv[8];
#pragma unroll
      for (int cc = 0; cc < 8; ++cc) rdv[cc] = rowk[cc] * rcpd;
      const bool pivR = (r == krt), pivC = (c == krt);
#pragma unroll
      for (int rr = 0; rr < 8; ++rr) {
        const double cv = colv[rr] * rcpd;
        const bool pr = pivR && (rr == kcl);
#pragma unroll
        for (int cc = 0; cc < 8; ++cc) {
          double gen = fma(-cv, rowk[cc], acc[rr][cc]);
          acc[rr][cc] = pr ? rdv[cc] : gen;
        }
      }
      if (pivC) {
#pragma unroll
        for (int cc = 0; cc < 8; ++cc) if (cc == kcl) {
#pragma unroll
          for (int rr = 0; rr < 8; ++rr) {
            const bool pr2 = pivR && (rr == kcl);
            acc[rr][cc] = pr2 ? -rcpd : colv[rr] * rcpd;
          }
        }
      }
      if (k < NN - 1) {
        const int pb2 = ((k + 1) & 1) << 7;
        const int krt2 = (k + 1) >> 3, kcl2 = (k + 1) & 7;
        if (r == krt2) {
#pragma unroll
          for (int rr = 0; rr < 8; ++rr) if (rr == kcl2) {
#pragma unroll
            for (int cc = 0; cc < 8; ++cc) ldsd[ROWB + pb2 + 8*c + cc] = acc[rr][cc];
          }
        }
        if (c == krt2) {
#pragma unroll
          for (int cc = 0; cc < 8; ++cc) if (cc == kcl2) {
#pragma unroll
            for (int rr = 0; rr < 8; ++rr) ldsd[COLB + pb2 + 8*r + rr] = acc[rr][cc];
          }
        }
      }
      __syncthreads();
    }
#pragma unroll
    for (int rr = 0; rr < 8; ++rr) {
      double2* dst = (double2*)(ldsd + (8*r+rr)*ROWD + 8*c);
#pragma unroll
      for (int t = 0; t < 4; ++t) dst[t] = make_double2(acc[rr][2*t], acc[rr][2*t+1]);
    }
  }
  __syncthreads();

  // ---------------- Stage 2: K = B (R B^T) in 8 blocks of 12 cols --------
  // Ownership: wave w holds cols 24w..24w+23 as 12 f32x2 pairs (blks 2w, 2w+1).
  f32x2 Kp[12], Kp2[12];
  for (int blk = 0; blk < 8; ++blk) {
    {
      const float* gp[6];
#pragma unroll
      for (int jj = 0; jj < 6; ++jj) {
        int it = 12*blk + 6*hh + jj;
        gp[jj] = (it < DI) ? (Gb + it*NN) : (Ab + (it - DI)*NN);
      }
      double a2[6] = {0,0,0,0,0,0};
#pragma unroll 4
      for (int t = 0; t < NN; ++t) {
        double rv = ldsd[t*ROWD + ia];
#pragma unroll
        for (int jj = 0; jj < 6; ++jj)
          a2[jj] = fma(rv, (double)gp[jj][t], a2[jj]);
      }
      double2* yst = (double2*)(ldsd + YBUF + ia*12 + 6*hh);
#pragma unroll
      for (int p = 0; p < 3; ++p) yst[p] = make_double2(a2[2*p], a2[2*p+1]);
    }
    __syncthreads();
    {
      const int r2 = (ia < NZ) ? ia : 0;
      const float* brow = (r2 < DI) ? (Gb + r2*NN) : (Ab + (r2 - DI)*NN);
      double a2[6] = {0,0,0,0,0,0};
#pragma unroll 4
      for (int t = 0; t < NN; ++t) {
        double bvv = (double)brow[t];
        const double2* yr = (const double2*)(ldsd + YBUF + t*12 + 6*hh);
        double2 y0 = yr[0], y1 = yr[1], y2 = yr[2];
        a2[0] = fma(bvv, y0.x, a2[0]); a2[1] = fma(bvv, y0.y, a2[1]);
        a2[2] = fma(bvv, y1.x, a2[2]); a2[3] = fma(bvv, y1.y, a2[3]);
        a2[4] = fma(bvv, y2.x, a2[4]); a2[5] = fma(bvv, y2.y, a2[5]);
      }
      if (ia < NZ) {
#pragma unroll
        for (int jj = 0; jj < 6; ++jj) ldsd[KBUF + (6*hh + jj)*NZ + ia] = a2[jj];
      }
    }
    __syncthreads();
    if (w == (blk >> 1)) {          // CONSTANT-index copies
      if ((blk & 1) == 0) { CPY12(0) } else { CPY12(6) }
    }
    __syncthreads();
  }

  // ---------------- Stage 3a: c = q - G^T h - A^T b ----------------
  {
    double s = 0;
#pragma unroll 8
    for (int jc = 0; jc < 48; ++jc) {
      int j = 48*hh + jc;
      double coef = (j < DI) ? ldsd[HB + j] : ldsd[BB + j - DI];
      const float* src = (j < DI) ? (Gb + j*NN) : (Ab + (j - DI)*NN);
      s = fma(-(double)src[ia], coef, s);
    }
    ldsd[CPART + hh*128 + ia] = s;
  }
  __syncthreads();
  if (tid < NN) ldsd[CB + tid] = ldsd[QBUF + tid] + ldsd[CPART + tid] + ldsd[CPART + 128 + tid];
  __syncthreads();

  // ---------------- Stage 3b: v1 = R c, v2 = R q ----------------
  {
    double a = 0, b2 = 0;
#pragma unroll 4
    for (int tt = 0; tt < 64; ++tt) {
      int t = 64*hh + tt;
      double rv = ldsd[t*ROWD + ia];
      a  = fma(rv, ldsd[CB + t], a);
      b2 = fma(rv, ldsd[QBUF + t], b2);
    }
    ldsd[VP + hh*128 + ia] = a;
    ldsd[VP + 256 + hh*128 + ia] = b2;
  }
  __syncthreads();
  if (tid < NN) {
    ldsd[V1 + tid] = ldsd[VP + tid] + ldsd[VP + 128 + tid];
    ldsd[V2 + tid] = ldsd[VP + 256 + tid] + ldsd[VP + 384 + tid];
  }
  __syncthreads();

  // ---------------- Stage 3c: base = B v1, qB = B v2, scalars ----------------
  {
    const int r2 = (ia < NZ) ? ia : 0;
    const float* brow = (r2 < DI) ? (Gb + r2*NN) : (Ab + (r2 - DI)*NN);
    const int voff = hh ? V2 : V1;
    double s = 0;
#pragma unroll 4
    for (int t = 0; t < NN; ++t) s = fma((double)brow[t], ldsd[voff + t], s);
    if (ia < NZ) ldsd[(hh ? QBV : BASEV) + ia] = s;
  }
  if (w == 0) {
    double pc = ldsd[V1+l]*ldsd[CB+l]   + ldsd[V1+64+l]*ldsd[CB+64+l];
    double pq = ldsd[V1+l]*ldsd[QBUF+l] + ldsd[V1+64+l]*ldsd[QBUF+64+l];
#pragma unroll
    for (int off = 32; off >= 1; off >>= 1) { pc += __shfl_xor(pc, off); pq += __shfl_xor(pq, off); }
    if (l == 0) { ldsd[CST] = pc; ldsd[CST+1] = pq; }
  }
  __syncthreads();

  // ---------------- Loop setup (4-wave matvec, obj stages as shadow work) ----------------
  // w0: lo cols 0..23 + lo-ring.           w1: lo cols 24..47 + stage-A (shadow).
  // w2: lo 48..63 + hi 0..7 (both chains) + tv (own-register zA).
  // w3: hi cols 8..31 + hi-ring + stage-B + flag (shadow).
  // Exchange: 4 packed b64 slots; uniform sum ((p0+p1)+(p2+p3)); f32 critical chain;
  // exact f64 state off-path (r7 recurrence, bit-identical across duplicating waves).
  const double baseA = ldsd[BASEV + l];
  const double baseB = ldsd[BASEV + 64 + lm];
  const double qvA   = ldsd[QBV + l];
  const double qvB   = ldsd[QBV + 64 + lm];
  const double hb2   = ldsd[HB + l] - baseA;       // h - baseA
  const double bb2   = baseB - ldsd[BB + lm];      // baseB - b
  const double S_uc  = ldsd[CST], S_qu = ldsd[CST + 1];
  double hnb = hb2, lb = bb2;                      // nu = 0, lam = 0 folded
  float hnbf = (float)hnb, lbf = (float)lb;        // f32 mirrors (critical chain)
  float zpl = 0.f, zph = 0.f;                      // z from last body (w0 lo / w3 hi)
  float zpl2 = 0.f, zph2 = 0.f;                    // w2's own z(it-1) for tv
  float zAf_lo = 0.f, zBf_lo = 0.f, zCf_lo = 0.f;  // w0 ring
  float zAf_hi = 0.f, zBf_hi = 0.f, zCf_hi = 0.f;  // w3 ring
  double res_prev = 1000.0, res_cur = -100.0;      // w3 obj recurrence

  // prologue: zero own P slot buf0; flags 0
  {
    *(float2*)&ldsd[PPK + w*64 + l] = make_float2(0.f, 0.f);
    if (tid == 0) { ldsd[FLG] = 0.0; ldsd[FLG + 1] = 0.0; }
  }

  // ---------------- ADMM loop: 1 barrier/body ----------------
  for (int it = 0; it < MAXIT + 3; ++it) {
    __syncthreads();
    const int buf = it & 1, nbuf = buf ^ 1;
    const int bprev = nbuf;                 // (it-1)&1
    const double fl = ldsd[FLG + bprev];    // flag stored body it-1 = decision for obj_{it-3}
    const float2* pb = (const float2*)(ldsd + PPK + buf*256);
    float2 p0 = pb[l], p1 = pb[64 + l], p2 = pb[128 + l], p3 = pb[192 + l];

    if (w == 0) {
      float slo = (p0.x + p1.x) + (p2.x + p3.x);
      float zflo = fabsf(hnbf - slo);
      if (it >= 3 && fl != 0.0) break;
      zCf_lo = zBf_lo; zBf_lo = zAf_lo; zAf_lo = zpl;   // ring: zA = z entering this body
      if (it < MAXIT) {
        zpl = zflo;
        double t = hnb - (double)slo; hnb = hb2 + fmin(t, 0.0); hnbf = (float)hnb;
        f32x2 A0 = {0.f,0.f}, A1 = A0, B0 = A0, B1 = A0;
        MV2(0,  zflo, 0)  MV2(2,  zflo, 4)  MV2(4,  zflo, 8)
        MV2(6,  zflo, 12) MV2(8,  zflo, 16) MV2(10, zflo, 20)
        f32x2 As = A0 + A1, Bs = B0 + B1;
        *(float2*)&ldsd[PPK + nbuf*256 + l] = make_float2(As.x + As.y, Bs.x + Bs.y);
      }
    } else if (w == 1) {
      // stage-A loads (shadow): tv(it-1) quartet, independent of this body's reads
      const int g = l & 15;
      const double* tq = ldsd + TVX + bprev*64;
      double a0 = tq[g], a1 = tq[g + 16], a2 = tq[g + 32], a3 = tq[g + 48];
      float slo = (p0.x + p1.x) + (p2.x + p3.x);
      float zflo = fabsf(hnbf - slo);
      if (it >= 3 && fl != 0.0) break;
      if (it < MAXIT) {
        double t = hnb - (double)slo; hnb = hb2 + fmin(t, 0.0); hnbf = (float)hnb;
        f32x2 A0 = {0.f,0.f}, A1 = A0, B0 = A0, B1 = A0;
        MV2(0,  zflo, 24) MV2(2,  zflo, 28) MV2(4,  zflo, 32)
        MV2(6,  zflo, 36) MV2(8,  zflo, 40) MV2(10, zflo, 44)
        f32x2 As = A0 + A1, Bs = B0 + B1;
        *(float2*)&ldsd[PPK + nbuf*256 + 64 + l] = make_float2(As.x + As.y, Bs.x + Bs.y);
      }
      // stage A store (pipeline it-1)
      if (l < 16 && it >= 1 && it <= MAXIT)
        ldsd[TV16 + buf*16 + l] = (a0 + a1) + (a2 + a3);
    } else if (w == 2) {
      float slo = (p0.x + p1.x) + (p2.x + p3.x);
      float shi = (p0.y + p1.y) + (p2.y + p3.y);
      float zflo = fabsf(hnbf - slo);
      float zfhi = lbf + shi;
      if (it >= 3 && fl != 0.0) break;
      const float zAl_f = zpl2, zAh_f = zph2;   // z(it-1), own registers
      if (it < MAXIT) {
        zpl2 = zflo; zph2 = zfhi;
        double t = hnb - (double)slo; hnb = hb2 + fmin(t, 0.0); hnbf = (float)hnb;
        double lamn = lb + (double)shi; lb = lamn + bb2; lbf = (float)lb;
        f32x2 A0 = {0.f,0.f}, A1 = A0, B0 = A0, B1 = A0;
        MV2(0,  zflo, 48) MV2(2,  zflo, 52) MV2(4,  zflo, 56) MV2(6,  zflo, 60)
        MV2(8,  zfhi, 0)  MV2(10, zfhi, 4)
        f32x2 As = A0 + A1, Bs = B0 + B1;
        *(float2*)&ldsd[PPK + nbuf*256 + 128 + l] = make_float2(As.x + As.y, Bs.x + Bs.y);
        // tv (pipeline it): y(it) sums + zA = z(it-1); interleaves with burst
        double zAl = (double)zAl_f;
        double yf  = (double)slo + baseA;
        double tvl = fma(qvA, zAl, -0.5*(zAl*(baseA + yf) + yf*yf));
        double zAh = (double)zAh_f;
        double yfB = (double)shi + baseB;
        double tvh = fma(qvB, zAh, -0.5*(zAh*(baseB + yfB) + yfB*yfB));
        ldsd[TVX + buf*64 + l] = tvl + ((l < 32) ? tvh : 0.0);
      }
    } else {
      // stage-B loads (shadow): sums of tv(it-2)
      double t1v[16];
      const double2* tp = (const double2*)(ldsd + TV16 + bprev*16);
#pragma unroll
      for (int u = 0; u < 8; ++u) { double2 vv = tp[u]; t1v[2*u] = vv.x; t1v[2*u+1] = vv.y; }
      float shi = (p0.y + p1.y) + (p2.y + p3.y);
      float zfhi = lbf + shi;
      if (it >= 3 && fl != 0.0) break;
      zCf_hi = zBf_hi; zBf_hi = zAf_hi; zAf_hi = zph;   // hi ring
      if (it < MAXIT) {
        zph = zfhi;
        double lamn = lb + (double)shi; lb = lamn + bb2; lbf = (float)lb;
        f32x2 A0 = {0.f,0.f}, A1 = A0, B0 = A0, B1 = A0;
        MV2(0,  zfhi, 8)  MV2(2,  zfhi, 12) MV2(4,  zfhi, 16)
        MV2(6,  zfhi, 20) MV2(8,  zfhi, 24) MV2(10, zfhi, 28)
        f32x2 As = A0 + A1, Bs = B0 + B1;
        *(float2*)&ldsd[PPK + nbuf*256 + 192 + l] = make_float2(As.x + As.y, Bs.x + Bs.y);
      }
      // stage B (pipeline it-2) -> flag; tree interleaves with burst
      if (it >= 2 && it <= MAXIT + 1) {
        double s1 = ((t1v[0] + t1v[1]) + (t1v[2] + t1v[3])) + ((t1v[4] + t1v[5]) + (t1v[6] + t1v[7]));
        double s2 = ((t1v[8] + t1v[9]) + (t1v[10] + t1v[11])) + ((t1v[12] + t1v[13]) + (t1v[14] + t1v[15]));
        double obj = (s1 + s2) - 0.5*S_uc + S_qu;
        res_prev = res_cur; res_cur = obj;
        if (l == 0)
          ldsd[FLG + buf] = (fabs(res_cur - res_prev) <= 1e-5 * fabs(res_prev)) ? 1.0 : 0.0;
      }
    }
  }

  // ---------------- Final: publish z (rings: zC = top-of-stopping-body) -> LDS ------
  if (w == 0) ldsd[ZBF + l] = (double)zCf_lo;
  if (w == 3 && l < 32) ldsd[ZBF + 64 + l] = (double)zCf_hi;
  __syncthreads();
  // x = R (c + B^T z); z read via broadcast LDS loads
  {
    double s = 0;
#pragma unroll 8
    for (int jc = 0; jc < 48; ++jc) {
      int j = 48*hh + jc;
      double zj = ldsd[ZBF + j];
      const float* src = (j < DI) ? (Gb + j*NN) : (Ab + (j - DI)*NN);
      s = fma((double)src[ia], zj, s);
    }
    ldsd[FPART + hh*128 + ia] = s;
  }
  __syncthreads();
  if (tid < NN) ldsd[RHSV + tid] = ldsd[CB + tid] + ldsd[FPART + tid] + ldsd[FPART + 128 + tid];
  __syncthreads();
  {
    double s = 0;
#pragma unroll 4
    for (int tt = 0; tt < 64; ++tt) {
      int t = 64*hh + tt;
      s = fma(ldsd[t*ROWD + ia], ldsd[RHSV + t], s);   // R[t][ia] = R[ia][t]
    }
    ldsd[XPART + hh*128 + ia] = s;
  }
  __syncthreads();
  if (tid < NN)
    out[(size_t)bidx * NN + tid] = (float)(ldsd[XPART + tid] + ldsd[XPART + 128 + tid]);
}

extern "C" void kernel_launch(void* const* d_in, const int* in_sizes, int n_in,
                              void* d_out, int out_size, void* d_ws, size_t ws_size,
                              hipStream_t stream) {
  (void)in_sizes; (void)n_in; (void)out_size; (void)d_ws; (void)ws_size;
  const float* Q = (const float*)d_in[0];
  const float* q = (const float*)d_in[1];
  const float* G = (const float*)d_in[2];
  const float* h = (const float*)d_in[3];
  const float* A = (const float*)d_in[4];
  const float* b = (const float*)d_in[5];
  float* out = (float*)d_out;
  const size_t lds_bytes = (size_t)LDS_DBL * sizeof(double);  // 160320
  altdiff_kernel<<<dim3(64), dim3(256), lds_bytes, stream>>>(Q, q, G, h, A, b, out);
}

// Round 10
// 599.879 us; speedup vs baseline: 2.1615x; 1.0887x over previous
//
#include <hip/hip_runtime.h>

#define NN 128
#define ME 32
#define DI 64
#define NZ 96
#define ROWD 130
#define MAXIT 5000

// ---- LDS layout (double offsets). R: [0, 16640). Total 20040 dbl = 160320 B <= 163840.
#define OFF_UN 16640
#define ROWB  (OFF_UN)           // [2][128] sweep row-k buffer (phase 2)
#define COLB  (OFF_UN + 256)     // [2][128] sweep col-k buffer (phase 2)
// loop window (3-slot exchange + dedicated obj wave):
#define PPK   (OFF_UN)           // [2][3][64] packed (lo,hi) f32 partials in b64 slots
#define ZEXL  (OFF_UN + 384)     // [2][64] f64 z_lo publish (w0 -> w3 tv)
#define ZEXH  (OFF_UN + 512)     // [2][32] f64 z_hi publish (w2 -> w3 tv)
#define TVX   (OFF_UN + 576)     // [2][64] f64 per-lane tv terms (w3 internal)
#define TV16  (OFF_UN + 704)     // [2][16] f64 stage-A sums (w3 internal)
#define FLG   (OFF_UN + 736)     // [2] convergence flag (double 0/1)
#define YBUF  (OFF_UN)           // [128][12] Y block (stage 2; dead before loop)
#define KBUF  (OFF_UN + 1536)    // [12][96] K cols (stage 2; dead before loop)
#define CPART (OFF_UN + 1024)    // [2][128] (stage 3a)
#define VP    (OFF_UN + 1280)    // [4][128] (stage 3b)
#define BASEV (OFF_UN + 1792)    // [96] (persists through loop)
#define QBV   (OFF_UN + 1888)    // [96] (persists through loop)
#define FPART (OFF_UN + 1024)    // [2][128] (final)
#define RHSV  (OFF_UN + 1280)    // [128] (final)
#define XPART (OFF_UN + 1408)    // [2][128] (final)
#define CB    (OFF_UN + 2688)    // [128] c
#define QBUF  (OFF_UN + 2816)    // [128] q
#define V1    (OFF_UN + 2944)    // [128] Rc
#define V2    (OFF_UN + 3072)    // [128] Rq
#define HB    (OFF_UN + 3200)    // [64]
#define BB    (OFF_UN + 3264)    // [32]
#define CST   (OFF_UN + 3296)    // [8]: 0=u.c 1=q.u
#define ZBF   (OFF_UN + 3304)    // [96] z publish (final)
#define LDS_DBL (OFF_UN + 3400)  // 20040

typedef __attribute__((ext_vector_type(2))) float f32x2;

// f32 SGPR broadcast. CONTRACT: source computed by all lanes of the wave.
__device__ __forceinline__ float rlf(float v, int lane) {
  return __uint_as_float((unsigned)__builtin_amdgcn_readlane((int)__float_as_uint(v), lane));
}
__device__ __forceinline__ f32x2 fma2(f32x2 a, f32x2 b, f32x2 c) {
  return __builtin_elementwise_fma(a, b, c);   // v_pk_fma_f32
}

// matvec step: 2 pairs (4 cols) with broadcast lanes L0..L0+3 of ZS
#define MV2(PA, ZS, L0) {                                                  \
    f32x2 z0 = { rlf(ZS, L0), rlf(ZS, (L0)+1) };                           \
    A0 = fma2(Kp[PA], z0, A0); B0 = fma2(Kp2[PA], z0, B0);                 \
    f32x2 z1 = { rlf(ZS, (L0)+2), rlf(ZS, (L0)+3) };                       \
    A1 = fma2(Kp[(PA)+1], z1, A1); B1 = fma2(Kp2[(PA)+1], z1, B1); }

// copy KBUF cols [KBASE, KBASE+CNT) into local K pairs starting at local col LBASE
#define CPYRANGE(LBASE, KBASE, CNT)                                        \
  _Pragma("unroll") for (int j = 0; j < (CNT); ++j) {                      \
    const int lj = (LBASE) + j, kc = (KBASE) + j;                          \
    float va = (float)ldsd[KBUF + kc*NZ + l];                              \
    float vb = (float)ldsd[KBUF + kc*NZ + 64 + lm];                        \
    if ((lj & 1) == 0) { Kp[lj>>1].x = va; Kp2[lj>>1].x = vb; }            \
    else               { Kp[lj>>1].y = va; Kp2[lj>>1].y = vb; }            \
  }

__global__ __launch_bounds__(256, 1) void altdiff_kernel(
    const float* __restrict__ Qg, const float* __restrict__ qg,
    const float* __restrict__ Gg, const float* __restrict__ hg,
    const float* __restrict__ Ag, const float* __restrict__ bg,
    float* __restrict__ out)
{
  extern __shared__ double ldsd[];

  const int bidx = blockIdx.x;
  const int tid  = threadIdx.x;
  const int w    = tid >> 6;     // wave 0..3
  const int l    = tid & 63;     // lane
  const int lm   = l & 31;
  const int ia   = tid & 127;    // 128-split index
  const int hh   = tid >> 7;     // 0..1 (wave-uniform)

  const float* Qb = Qg + (size_t)bidx * NN * NN;
  const float* Ab = Ag + (size_t)bidx * ME * NN;
  const float* Gb = Gg + (size_t)bidx * DI * NN;
  const float* qb = qg + (size_t)bidx * NN;
  const float* hb = hg + (size_t)bidx * DI;
  const float* bv = bg + (size_t)bidx * ME;

  // stage h, b, q (f64)
  if (tid < DI) ldsd[HB + tid] = (double)hb[tid];
  else if (tid < DI + ME) ldsd[BB + tid - DI] = (double)bv[tid - DI];
  if (tid >= 128) ldsd[QBUF + tid - 128] = (double)qb[tid - 128];

  const int r = tid >> 4, c = tid & 15;   // 8x8 register tile at rows 8r.., cols 8c..
  double acc[8][8];                       // ALL indices compile-time constant (no scratch)

  // ---------------- Phase 1: M = Q + A^T A + G^T G (f64) -> registers ----------------
  {
    const float4* Q4 = (const float4*)Qb;
#pragma unroll
    for (int rr = 0; rr < 8; ++rr) {
      float4 q0 = Q4[((8*r+rr) << 5) + 2*c];
      float4 q1 = Q4[((8*r+rr) << 5) + 2*c + 1];
      acc[rr][0]=(double)q0.x; acc[rr][1]=(double)q0.y; acc[rr][2]=(double)q0.z; acc[rr][3]=(double)q0.w;
      acc[rr][4]=(double)q1.x; acc[rr][5]=(double)q1.y; acc[rr][6]=(double)q1.z; acc[rr][7]=(double)q1.w;
    }
    const float4* A4 = (const float4*)Ab;
    for (int m = 0; m < ME; ++m) {
      float4 u0 = A4[(m << 5) + 2*r], u1 = A4[(m << 5) + 2*r + 1];
      float4 v0 = A4[(m << 5) + 2*c], v1 = A4[(m << 5) + 2*c + 1];
      double uu[8] = {(double)u0.x,(double)u0.y,(double)u0.z,(double)u0.w,
                      (double)u1.x,(double)u1.y,(double)u1.z,(double)u1.w};
      double vv[8] = {(double)v0.x,(double)v0.y,(double)v0.z,(double)v0.w,
                      (double)v1.x,(double)v1.y,(double)v1.z,(double)v1.w};
#pragma unroll
      for (int rr = 0; rr < 8; ++rr)
#pragma unroll
        for (int cc = 0; cc < 8; ++cc)
          acc[rr][cc] = fma(uu[rr], vv[cc], acc[rr][cc]);
    }
    const float4* G4 = (const float4*)Gb;
    for (int d = 0; d < DI; ++d) {
      float4 u0 = G4[(d << 5) + 2*r], u1 = G4[(d << 5) + 2*r + 1];
      float4 v0 = G4[(d << 5) + 2*c], v1 = G4[(d << 5) + 2*c + 1];
      double uu[8] = {(double)u0.x,(double)u0.y,(double)u0.z,(double)u0.w,
                      (double)u1.x,(double)u1.y,(double)u1.z,(double)u1.w};
      double vv[8] = {(double)v0.x,(double)v0.y,(double)v0.z,(double)v0.w,
                      (double)v1.x,(double)v1.y,(double)v1.z,(double)v1.w};
#pragma unroll
      for (int rr = 0; rr < 8; ++rr)
#pragma unroll
        for (int cc = 0; cc < 8; ++cc)
          acc[rr][cc] = fma(uu[rr], vv[cc], acc[rr][cc]);
    }
  }

  // ---------------- Phase 2: register-tile sweep, 1 barrier/pivot, double-buffered ----------
  {
    if (r == 0) {
#pragma unroll
      for (int cc = 0; cc < 8; ++cc) ldsd[ROWB + 8*c + cc] = acc[0][cc];
    }
    if (c == 0) {
#pragma unroll
      for (int rr = 0; rr < 8; ++rr) ldsd[COLB + 8*r + rr] = acc[rr][0];
    }
    __syncthreads();
    for (int k = 0; k < NN; ++k) {
      const int pb = (k & 1) << 7;
      const int krt = k >> 3, kcl = k & 7;
      double rowk[8], colv[8];
#pragma unroll
      for (int cc = 0; cc < 8; ++cc) rowk[cc] = ldsd[ROWB + pb + 8*c + cc];
#pragma unroll
      for (int rr = 0; rr < 8; ++rr) colv[rr] = ldsd[COLB + pb + 8*r + rr];
      const double dkk  = ldsd[ROWB + pb + k];     // same-address broadcast
      const double rcpd = 1.0 / dkk;               // pivots >= 1 (M >= I)
      double rdv[8];
#pragma unroll
      for (int cc = 0; cc < 8; ++cc) rdv[cc] = rowk[cc] * rcpd;
      const bool pivR = (r == krt), pivC = (c == krt);
#pragma unroll
      for (int rr = 0; rr < 8; ++rr) {
        const double cv = colv[rr] * rcpd;
        const bool pr = pivR && (rr == kcl);
#pragma unroll
        for (int cc = 0; cc < 8; ++cc) {
          double gen = fma(-cv, rowk[cc], acc[rr][cc]);
          acc[rr][cc] = pr ? rdv[cc] : gen;
        }
      }
      if (pivC) {
#pragma unroll
        for (int cc = 0; cc < 8; ++cc) if (cc == kcl) {
#pragma unroll
          for (int rr = 0; rr < 8; ++rr) {
            const bool pr2 = pivR && (rr == kcl);
            acc[rr][cc] = pr2 ? -rcpd : colv[rr] * rcpd;
          }
        }
      }
      if (k < NN - 1) {
        const int pb2 = ((k + 1) & 1) << 7;
        const int krt2 = (k + 1) >> 3, kcl2 = (k + 1) & 7;
        if (r == krt2) {
#pragma unroll
          for (int rr = 0; rr < 8; ++rr) if (rr == kcl2) {
#pragma unroll
            for (int cc = 0; cc < 8; ++cc) ldsd[ROWB + pb2 + 8*c + cc] = acc[rr][cc];
          }
        }
        if (c == krt2) {
#pragma unroll
          for (int cc = 0; cc < 8; ++cc) if (cc == kcl2) {
#pragma unroll
            for (int rr = 0; rr < 8; ++rr) ldsd[COLB + pb2 + 8*r + rr] = acc[rr][cc];
          }
        }
      }
      __syncthreads();
    }
#pragma unroll
    for (int rr = 0; rr < 8; ++rr) {
      double2* dst = (double2*)(ldsd + (8*r+rr)*ROWD + 8*c);
#pragma unroll
      for (int t = 0; t < 4; ++t) dst[t] = make_double2(acc[rr][2*t], acc[rr][2*t+1]);
    }
  }
  __syncthreads();

  // ---------------- Stage 2: K = B (R B^T) in 8 blocks of 12 cols --------
  // Ownership: w0 cols 0..31, w1 cols 32..63, w2 cols 64..95 (16 f32x2 pairs each).
  // Wave 3 holds nothing (objective wave).
  f32x2 Kp[16], Kp2[16];
  for (int blk = 0; blk < 8; ++blk) {
    {
      const float* gp[6];
#pragma unroll
      for (int jj = 0; jj < 6; ++jj) {
        int it = 12*blk + 6*hh + jj;
        gp[jj] = (it < DI) ? (Gb + it*NN) : (Ab + (it - DI)*NN);
      }
      double a2[6] = {0,0,0,0,0,0};
#pragma unroll 4
      for (int t = 0; t < NN; ++t) {
        double rv = ldsd[t*ROWD + ia];
#pragma unroll
        for (int jj = 0; jj < 6; ++jj)
          a2[jj] = fma(rv, (double)gp[jj][t], a2[jj]);
      }
      double2* yst = (double2*)(ldsd + YBUF + ia*12 + 6*hh);
#pragma unroll
      for (int p = 0; p < 3; ++p) yst[p] = make_double2(a2[2*p], a2[2*p+1]);
    }
    __syncthreads();
    {
      const int r2 = (ia < NZ) ? ia : 0;
      const float* brow = (r2 < DI) ? (Gb + r2*NN) : (Ab + (r2 - DI)*NN);
      double a2[6] = {0,0,0,0,0,0};
#pragma unroll 4
      for (int t = 0; t < NN; ++t) {
        double bvv = (double)brow[t];
        const double2* yr = (const double2*)(ldsd + YBUF + t*12 + 6*hh);
        double2 y0 = yr[0], y1 = yr[1], y2 = yr[2];
        a2[0] = fma(bvv, y0.x, a2[0]); a2[1] = fma(bvv, y0.y, a2[1]);
        a2[2] = fma(bvv, y1.x, a2[2]); a2[3] = fma(bvv, y1.y, a2[3]);
        a2[4] = fma(bvv, y2.x, a2[4]); a2[5] = fma(bvv, y2.y, a2[5]);
      }
      if (ia < NZ) {
#pragma unroll
        for (int jj = 0; jj < 6; ++jj) ldsd[KBUF + (6*hh + jj)*NZ + ia] = a2[jj];
      }
    }
    __syncthreads();
    // copy-out: constant indices per (wave, blk) arm
    if (w == 0) {
      if (blk == 0)      { CPYRANGE(0,  0, 12) }
      else if (blk == 1) { CPYRANGE(12, 0, 12) }
      else if (blk == 2) { CPYRANGE(24, 0, 8) }
    } else if (w == 1) {
      if (blk == 2)      { CPYRANGE(0,  8, 4) }
      else if (blk == 3) { CPYRANGE(4,  0, 12) }
      else if (blk == 4) { CPYRANGE(16, 0, 12) }
      else if (blk == 5) { CPYRANGE(28, 0, 4) }
    } else if (w == 2) {
      if (blk == 5)      { CPYRANGE(0,  4, 8) }
      else if (blk == 6) { CPYRANGE(8,  0, 12) }
      else if (blk == 7) { CPYRANGE(20, 0, 12) }
    }
    __syncthreads();
  }

  // ---------------- Stage 3a: c = q - G^T h - A^T b ----------------
  {
    double s = 0;
#pragma unroll 8
    for (int jc = 0; jc < 48; ++jc) {
      int j = 48*hh + jc;
      double coef = (j < DI) ? ldsd[HB + j] : ldsd[BB + j - DI];
      const float* src = (j < DI) ? (Gb + j*NN) : (Ab + (j - DI)*NN);
      s = fma(-(double)src[ia], coef, s);
    }
    ldsd[CPART + hh*128 + ia] = s;
  }
  __syncthreads();
  if (tid < NN) ldsd[CB + tid] = ldsd[QBUF + tid] + ldsd[CPART + tid] + ldsd[CPART + 128 + tid];
  __syncthreads();

  // ---------------- Stage 3b: v1 = R c, v2 = R q ----------------
  {
    double a = 0, b2 = 0;
#pragma unroll 4
    for (int tt = 0; tt < 64; ++tt) {
      int t = 64*hh + tt;
      double rv = ldsd[t*ROWD + ia];
      a  = fma(rv, ldsd[CB + t], a);
      b2 = fma(rv, ldsd[QBUF + t], b2);
    }
    ldsd[VP + hh*128 + ia] = a;
    ldsd[VP + 256 + hh*128 + ia] = b2;
  }
  __syncthreads();
  if (tid < NN) {
    ldsd[V1 + tid] = ldsd[VP + tid] + ldsd[VP + 128 + tid];
    ldsd[V2 + tid] = ldsd[VP + 256 + tid] + ldsd[VP + 384 + tid];
  }
  __syncthreads();

  // ---------------- Stage 3c: base = B v1, qB = B v2, scalars ----------------
  {
    const int r2 = (ia < NZ) ? ia : 0;
    const float* brow = (r2 < DI) ? (Gb + r2*NN) : (Ab + (r2 - DI)*NN);
    const int voff = hh ? V2 : V1;
    double s = 0;
#pragma unroll 4
    for (int t = 0; t < NN; ++t) s = fma((double)brow[t], ldsd[voff + t], s);
    if (ia < NZ) ldsd[(hh ? QBV : BASEV) + ia] = s;
  }
  if (w == 0) {
    double pc = ldsd[V1+l]*ldsd[CB+l]   + ldsd[V1+64+l]*ldsd[CB+64+l];
    double pq = ldsd[V1+l]*ldsd[QBUF+l] + ldsd[V1+64+l]*ldsd[QBUF+64+l];
#pragma unroll
    for (int off = 32; off >= 1; off >>= 1) { pc += __shfl_xor(pc, off); pq += __shfl_xor(pq, off); }
    if (l == 0) { ldsd[CST] = pc; ldsd[CST+1] = pq; }
  }
  __syncthreads();

  // ---------------- Loop setup ----------------
  // w0: cols 0..31 (z_lo lanes 0-31) + lo chain + lo ring + ZEXL publish.
  // w1: cols 32..63 (z_lo lanes 32-63) + lo chain (duplicate state, bit-identical).
  // w2: cols 64..95 (z_hi lanes 0-31) + hi chain + hi ring + ZEXH publish.
  // w3: objective pipeline (tv -> stage A -> stage B -> flag).
  // Exchange: 3 packed b64 slots; own partial reg-resident; 2 remote reads (parallel).
  // All waves sum slots in the SAME order (s0+s1)+s2 so duplicated state matches.
  const double baseA = ldsd[BASEV + l];
  const double baseB = ldsd[BASEV + 64 + lm];
  const double qvA   = ldsd[QBV + l];
  const double qvB   = ldsd[QBV + 64 + lm];
  const double hb2   = ldsd[HB + l] - baseA;       // h - baseA
  const double bb2   = baseB - ldsd[BB + lm];      // baseB - b
  const double S_uc  = ldsd[CST], S_qu = ldsd[CST + 1];
  double hnb = hb2, lb = bb2;                      // nu = 0, lam = 0 folded
  double zlo = 0.0, zhi = 0.0;
  double zAlo = 0.0, zAhi = 0.0, zBlo = 0.0, zBhi = 0.0, zClo = 0.0, zChi = 0.0;
  double res_prev = 1000.0, res_cur = -100.0;      // w3 obj recurrence
  float2 own = make_float2(0.f, 0.f);              // own partial (w0/w1/w2), reg-resident

  // prologue: zero P buf0 slots; z(-1)=0 into ZEX buf1; flags 0
  {
    if (w < 3) *(float2*)&ldsd[PPK + w*64 + l] = make_float2(0.f, 0.f);
    if (w == 0) ldsd[ZEXL + 64 + l] = 0.0;
    if (w == 2 && l < 32) ldsd[ZEXH + 32 + l] = 0.0;
    if (tid == 0) { ldsd[FLG] = 0.0; ldsd[FLG + 1] = 0.0; }
  }

  // ---------------- ADMM loop: 1 barrier/body ----------------
  for (int it = 0; it < MAXIT + 3; ++it) {
    __syncthreads();
    const int buf = it & 1, nbuf = buf ^ 1;
    const int bprev = nbuf;                 // (it-1)&1
    const double fl = ldsd[FLG + bprev];    // flag stored body it-1 = decision for obj_{it-3}
    const float2* pb = (const float2*)(ldsd + PPK + buf*192);

    if (w == 0) {
      float2 s1v = pb[64 + l], s2v = pb[128 + l];
      float slo = (own.x + s1v.x) + s2v.x;            // (s0+s1)+s2
      double t = hnb - (double)slo;
      float zflo = (float)fabs(t);
      if (it >= 3 && fl != 0.0) break;
      zClo = zBlo; zBlo = zAlo; zAlo = zlo;
      if (it < MAXIT) {
        zlo = fabs(t);
        ldsd[ZEXL + buf*64 + l] = zlo;
        hnb = hb2 + fmin(t, 0.0);                     // = hb2 - relu(-t)
        f32x2 A0 = {0.f, 0.f}, A1 = A0, B0 = A0, B1 = A0;
        MV2(0,  zflo, 0)  MV2(2,  zflo, 4)  MV2(4,  zflo, 8)  MV2(6,  zflo, 12)
        MV2(8,  zflo, 16) MV2(10, zflo, 20) MV2(12, zflo, 24) MV2(14, zflo, 28)
        f32x2 As = A0 + A1, Bs = B0 + B1;
        float2 np = make_float2(As.x + As.y, Bs.x + Bs.y);
        *(float2*)&ldsd[PPK + nbuf*192 + l] = np;
        own = np;
      }
    } else if (w == 1) {
      float2 s0v = pb[l], s2v = pb[128 + l];
      float slo = (s0v.x + own.x) + s2v.x;            // (s0+s1)+s2
      double t = hnb - (double)slo;
      float zflo = (float)fabs(t);
      if (it >= 3 && fl != 0.0) break;
      if (it < MAXIT) {
        hnb = hb2 + fmin(t, 0.0);
        f32x2 A0 = {0.f, 0.f}, A1 = A0, B0 = A0, B1 = A0;
        MV2(0,  zflo, 32) MV2(2,  zflo, 36) MV2(4,  zflo, 40) MV2(6,  zflo, 44)
        MV2(8,  zflo, 48) MV2(10, zflo, 52) MV2(12, zflo, 56) MV2(14, zflo, 60)
        f32x2 As = A0 + A1, Bs = B0 + B1;
        float2 np = make_float2(As.x + As.y, Bs.x + Bs.y);
        *(float2*)&ldsd[PPK + nbuf*192 + 64 + l] = np;
        own = np;
      }
    } else if (w == 2) {
      float2 s0v = pb[l], s1v = pb[64 + l];
      float shi = (s0v.y + s1v.y) + own.y;            // (s0+s1)+s2
      double lamn = lb + (double)shi;
      float zfhi = (float)lamn;
      if (it >= 3 && fl != 0.0) break;
      zChi = zBhi; zBhi = zAhi; zAhi = zhi;
      if (it < MAXIT) {
        zhi = lamn;
        lb = lamn + bb2;
        if (l < 32) ldsd[ZEXH + buf*32 + l] = lamn;
        f32x2 A0 = {0.f, 0.f}, A1 = A0, B0 = A0, B1 = A0;
        MV2(0,  zfhi, 0)  MV2(2,  zfhi, 4)  MV2(4,  zfhi, 8)  MV2(6,  zfhi, 12)
        MV2(8,  zfhi, 16) MV2(10, zfhi, 20) MV2(12, zfhi, 24) MV2(14, zfhi, 28)
        f32x2 As = A0 + A1, Bs = B0 + B1;
        float2 np = make_float2(As.x + As.y, Bs.x + Bs.y);
        *(float2*)&ldsd[PPK + nbuf*192 + 128 + l] = np;
        own = np;
      }
    } else {
      // ---------------- w3: objective pipeline ----------------
      float2 v0 = pb[l], v1 = pb[64 + l], v2 = pb[128 + l];
      const double zAl = ldsd[ZEXL + bprev*64 + l];    // z_top(it) = z(it-1)
      const double zAh = ldsd[ZEXH + bprev*32 + lm];
      const int g = l & 15;
      const double* tq = ldsd + TVX + bprev*64;        // tv(it-1), stride-16 quartet
      double a0 = tq[g], a1 = tq[g + 16], a2 = tq[g + 32], a3 = tq[g + 48];
      double t1v[16];
      const double2* tp = (const double2*)(ldsd + TV16 + bprev*16);  // sums of tv(it-2)
#pragma unroll
      for (int u = 0; u < 8; ++u) { double2 vv = tp[u]; t1v[2*u] = vv.x; t1v[2*u+1] = vv.y; }
      if (it >= 3 && fl != 0.0) break;
      // stage tv (pipeline it)
      if (it < MAXIT) {
        float slo_f = (v0.x + v1.x) + v2.x;
        float shi_f = (v0.y + v1.y) + v2.y;
        double yf  = (double)slo_f + baseA;
        double tvl = fma(qvA, zAl, -0.5*(zAl*(baseA + yf) + yf*yf));
        double yfB = (double)shi_f + baseB;
        double tvh = fma(qvB, zAh, -0.5*(zAh*(baseB + yfB) + yfB*yfB));
        ldsd[TVX + buf*64 + l] = tvl + ((l < 32) ? tvh : 0.0);
      }
      // stage A (pipeline it-1)
      if (l < 16 && it >= 1 && it <= MAXIT)
        ldsd[TV16 + buf*16 + l] = (a0 + a1) + (a2 + a3);
      // stage B (pipeline it-2) -> flag
      if (it >= 2 && it <= MAXIT + 1) {
        double s1 = ((t1v[0] + t1v[1]) + (t1v[2] + t1v[3])) + ((t1v[4] + t1v[5]) + (t1v[6] + t1v[7]));
        double s2 = ((t1v[8] + t1v[9]) + (t1v[10] + t1v[11])) + ((t1v[12] + t1v[13]) + (t1v[14] + t1v[15]));
        double obj = (s1 + s2) - 0.5*S_uc + S_qu;
        res_prev = res_cur; res_cur = obj;
        if (l == 0)
          ldsd[FLG + buf] = (fabs(res_cur - res_prev) <= 1e-5 * fabs(res_prev)) ? 1.0 : 0.0;
      }
    }
  }

  // ---------------- Final: publish z (rings: zC = top-of-stopping-body) -> LDS ------
  if (w == 0) ldsd[ZBF + l] = zClo;
  if (w == 2 && l < 32) ldsd[ZBF + 64 + l] = zChi;
  __syncthreads();
  // x = R (c + B^T z); z read via broadcast LDS loads
  {
    double s = 0;
#pragma unroll 8
    for (int jc = 0; jc < 48; ++jc) {
      int j = 48*hh + jc;
      double zj = ldsd[ZBF + j];
      const float* src = (j < DI) ? (Gb + j*NN) : (Ab + (j - DI)*NN);
      s = fma((double)src[ia], zj, s);
    }
    ldsd[FPART + hh*128 + ia] = s;
  }
  __syncthreads();
  if (tid < NN) ldsd[RHSV + tid] = ldsd[CB + tid] + ldsd[FPART + tid] + ldsd[FPART + 128 + tid];
  __syncthreads();
  {
    double s = 0;
#pragma unroll 4
    for (int tt = 0; tt < 64; ++tt) {
      int t = 64*hh + tt;
      s = fma(ldsd[t*ROWD + ia], ldsd[RHSV + t], s);   // R[t][ia] = R[ia][t]
    }
    ldsd[XPART + hh*128 + ia] = s;
  }
  __syncthreads();
  if (tid < NN)
    out[(size_t)bidx * NN + tid] = (float)(ldsd[XPART + tid] + ldsd[XPART + 128 + tid]);
}

extern "C" void kernel_launch(void* const* d_in, const int* in_sizes, int n_in,
                              void* d_out, int out_size, void* d_ws, size_t ws_size,
                              hipStream_t stream) {
  (void)in_sizes; (void)n_in; (void)out_size; (void)d_ws; (void)ws_size;
  const float* Q = (const float*)d_in[0];
  const float* q = (const float*)d_in[1];
  const float* G = (const float*)d_in[2];
  const float* h = (const float*)d_in[3];
  const float* A = (const float*)d_in[4];
  const float* b = (const float*)d_in[5];
  float* out = (float*)d_out;
  const size_t lds_bytes = (size_t)LDS_DBL * sizeof(double);  // 160320
  altdiff_kernel<<<dim3(64), dim3(256), lds_bytes, stream>>>(Q, q, G, h, A, b, out);
}